// Round 13
// baseline (108.646 us; speedup 1.0000x reference)
//
#include <hip/hip_runtime.h>
#include <hip/hip_bf16.h>
#include <stdint.h>

typedef __attribute__((ext_vector_type(4))) float f32x4;
typedef __attribute__((ext_vector_type(16))) float f32x16;
typedef __attribute__((ext_vector_type(8))) short bf16x8;
typedef __attribute__((ext_vector_type(4))) short bf16x4;
typedef unsigned short ushort_t;

#define QSCALE 0.18033688f   // 0.125 * log2(e): softmax runs in exp2 domain

__device__ inline short f2bf(float f) {
  unsigned u = __builtin_bit_cast(unsigned, f);
  u += 0x7fffu + ((u >> 16) & 1u);   // RNE
  return (short)(u >> 16);
}

__device__ inline void gload_lds16(const void* g, void* l) {
  __builtin_amdgcn_global_load_lds(
      (const __attribute__((address_space(1))) void*)g,
      (__attribute__((address_space(3))) void*)l, 16, 0, 0);
}

__device__ inline unsigned cvtpk(float a, float b) {
  unsigned r;
  asm("v_cvt_pk_bf16_f32 %0, %1, %2" : "=v"(r) : "v"(a), "v"(b));
  return r;
}

__device__ inline void swap32u(unsigned& a, unsigned& b) {
  asm("v_permlane32_swap_b32 %0, %1" : "+v"(a), "+v"(b));
}

// ---------------- fused fp32 -> bf16 convert (x, w_qkv, w_proj) ----------------
__global__ __launch_bounds__(256) void cvt_all(const float* __restrict__ x,
                                               const float* __restrict__ wq,
                                               const float* __restrict__ wp,
                                               short* __restrict__ Xb,
                                               short* __restrict__ Wq,
                                               short* __restrict__ Wp) {
  int i = blockIdx.x * 256 + threadIdx.x;   // vec8 index, total 1048576
  const float* s;
  short* d;
  int off;
  if (i < 524288)       { s = x;  d = Xb; off = i; }
  else if (i < 917504)  { s = wq; d = Wq; off = i - 524288; }
  else                  { s = wp; d = Wp; off = i - 917504; }
  const float4* sv = (const float4*)s;
  float4 a = sv[2 * off], b = sv[2 * off + 1];
  bf16x8 o;
  o[0] = f2bf(a.x); o[1] = f2bf(a.y); o[2] = f2bf(a.z); o[3] = f2bf(a.w);
  o[4] = f2bf(b.x); o[5] = f2bf(b.y); o[6] = f2bf(b.z); o[7] = f2bf(b.w);
  ((bf16x8*)d)[off] = o;
}

// ---------------- 128x128 BK=64 double-buffer counted-vmcnt GEMM: C = A * B^T ----------------
// T1 XCD swizzle: 1-D grid, xcd = id&7 owns BXPX consecutive B-column panels.
// SPLITV=1 (qkv): cols<2048 -> QK (q pre-scaled); cols>=2048 -> Vtg via LDS transpose.
template <int F32OUT, int SPLITV, int BXPX>
__global__ __launch_bounds__(256, 2) void gemm_db(const short* __restrict__ A,
                                                  const short* __restrict__ B,
                                                  void* __restrict__ Cv,
                                                  short* __restrict__ Vtg,
                                                  const float* __restrict__ bias,
                                                  int scale_cols, float scale_val,
                                                  int M, int N, int K) {
  __shared__ char smem[65536];
  short* Ab0 = (short*)smem;                 // [2][128*64]
  short* Bb0 = (short*)(smem + 32768);       // [2][128*64]
  const int tid = threadIdx.x, wv = tid >> 6, ln = tid & 63;
  const int wm = wv >> 1, wn = wv & 1;       // 2x2 waves, 64x64 each
  const int id = blockIdx.x;
  const int xcd = id & 7, local = id >> 3;
  const int bx = xcd * BXPX + local % BXPX;
  const int by = local / BXPX;
  const int bn0 = bx * 128, bm0 = by * 128;
  const int nt = K >> 6;                     // BK = 64

  const int srow = ln >> 3;
  const int scol = ((ln & 7) ^ (ln >> 3)) * 8;
  const int fln = ln & 15;
  const int fk = ln >> 4;

  f32x4 acc[4][4] = {};

  auto stage = [&](int t, int s) {
    const size_t k0 = (size_t)t << 6;
#pragma unroll
    for (int rd = 0; rd < 4; rd++) {
      const int ch = 4 * wv + rd;
      gload_lds16(A + (size_t)(bm0 + ch * 8 + srow) * K + k0 + scol,
                  (char*)(Ab0 + s * 8192) + ch * 1024);
      gload_lds16(B + (size_t)(bn0 + ch * 8 + srow) * K + k0 + scol,
                  (char*)(Bb0 + s * 8192) + ch * 1024);
    }
  };

  stage(0, 0);
  stage(1, 1);
  asm volatile("s_waitcnt vmcnt(8)" ::: "memory");
  __builtin_amdgcn_s_barrier();
  __builtin_amdgcn_sched_barrier(0);

  for (int t = 0; t < nt; t++) {
    const int s = t & 1;
    const char* Ap = (const char*)(Ab0 + s * 8192);
    const char* Bp = (const char*)(Bb0 + s * 8192);

    bf16x8 af[4][2], bf[4][2];
#pragma unroll
    for (int m = 0; m < 4; m++) {
      const int R = wm * 64 + m * 16 + fln;
#pragma unroll
      for (int kk = 0; kk < 2; kk++)
        af[m][kk] = *(const bf16x8*)(Ap + R * 128 + ((((kk << 2) | fk) ^ (R & 7)) << 4));
    }
#pragma unroll
    for (int n = 0; n < 4; n++) {
      const int R = wn * 64 + n * 16 + fln;
#pragma unroll
      for (int kk = 0; kk < 2; kk++)
        bf[n][kk] = *(const bf16x8*)(Bp + R * 128 + ((((kk << 2) | fk) ^ (R & 7)) << 4));
    }

    __builtin_amdgcn_s_setprio(1);
#pragma unroll
    for (int kk = 0; kk < 2; kk++)
#pragma unroll
      for (int m = 0; m < 4; m++)
#pragma unroll
        for (int n = 0; n < 4; n++)
          acc[m][n] = __builtin_amdgcn_mfma_f32_16x16x32_bf16(af[m][kk], bf[n][kk], acc[m][n], 0, 0, 0);
    __builtin_amdgcn_s_setprio(0);

    if (t + 1 < nt) {
      __builtin_amdgcn_s_barrier();
      if (t + 2 < nt) {
        stage(t + 2, s);
        asm volatile("s_waitcnt vmcnt(8)" ::: "memory");
      } else {
        asm volatile("s_waitcnt vmcnt(0)" ::: "memory");
      }
      __builtin_amdgcn_s_barrier();
      __builtin_amdgcn_sched_barrier(0);
    }
  }

  // ---------- epilogue ----------
  if constexpr (SPLITV) {
    if (bn0 >= 2048) {
      __syncthreads();
      short* Vl = (short*)smem;   // [128 f][136 tok]
#pragma unroll
      for (int m = 0; m < 4; m++) {
        const int tok0 = wm * 64 + m * 16 + fk * 4;
#pragma unroll
        for (int n = 0; n < 4; n++) {
          const int f_loc = wn * 64 + n * 16 + fln;
          bf16x4 w;
#pragma unroll
          for (int j = 0; j < 4; j++) w[j] = f2bf(acc[m][n][j]);
          *(bf16x4*)(Vl + f_loc * 136 + tok0) = w;
        }
      }
      __syncthreads();
      const int fbase = bn0 - 2048, bb = bm0 >> 11, ntok0 = bm0 & 2047;
#pragma unroll
      for (int pass = 0; pass < 8; pass++) {
        const int f_loc = wv * 32 + pass * 4 + (ln >> 4);
        const int f = fbase + f_loc;
        const int g = (bb * 16 + (f >> 6)) * 64 + (f & 63);
        bf16x8 w = *(const bf16x8*)(Vl + f_loc * 136 + (ln & 15) * 8);
        *(bf16x8*)(Vtg + (size_t)g * 2048 + ntok0 + (ln & 15) * 8) = w;
      }
      return;
    }
  }

  const int r0 = bm0 + wm * 64, c0 = bn0 + wn * 64;
  const int fg4 = fk * 4;
#pragma unroll
  for (int m = 0; m < 4; m++) {
    const int row0 = r0 + m * 16 + fg4;
#pragma unroll
    for (int n = 0; n < 4; n++) {
      const int col = c0 + n * 16 + fln;
      if constexpr (SPLITV) {
        const float sc = (col < scale_cols) ? scale_val : 1.0f;
#pragma unroll
        for (int j = 0; j < 4; j++)
          ((short*)Cv)[(size_t)(row0 + j) * 2048 + col] = f2bf(acc[m][n][j] * sc);
      } else {
#pragma unroll
        for (int j = 0; j < 4; j++) {
          float v = acc[m][n][j];
          if (col < scale_cols) v *= scale_val;
          if (F32OUT) ((float*)Cv)[(size_t)(row0 + j) * N + col] = v + bias[col];
          else        ((short*)Cv)[(size_t)(row0 + j) * N + col] = f2bf(v);
        }
      }
    }
  }
}

// ---------------- flash attention: 64 q/wave, R8-style 2-buffer __syncthreads sync ----------------
// QK: [4096][2048] bf16 (q pre-scaled, k at +1024). Vtg: [(b*16+h)*64+d][2048] bf16.
// Grid 256 (XCD-swizzled), 256 thr = 4 waves x 64 q-rows. Each K/V A-frag read feeds
// TWO q-set MFMAs (set A: q=lq, set B: q=lq+32). 32 tiles of 64 kv.
__global__ __launch_bounds__(256, 2) void attn_fwd(const short* __restrict__ QK,
                                                   const short* __restrict__ Vtg,
                                                   short* __restrict__ AO) {
  __shared__ short Ks[2][64 * 64];   // [kv][d], XOR-swizzled 16B chunks
  __shared__ short Vt[2][64 * 64];   // [d][kv], XOR-swizzled
  const int tid = threadIdx.x, wv = tid >> 6, ln = tid & 63;
  const int lq = ln & 31, hi = ln >> 5;
  const int id = blockIdx.x;
  const int c = (id & 7) * 32 + (id >> 3);   // XCD swizzle: 4 heads per XCD
  const int qt = c & 7, bh = c >> 3;
  const int b = bh >> 4, h = bh & 15;
  const short* base = QK + (size_t)(b * 2048) * 2048 + h * 64;
  const short* Kg = base + 1024;
  const short* Vg = Vtg + (size_t)bh * 64 * 2048;
  const int qrowA = qt * 256 + wv * 64 + lq;   // q-set A; set B = +32

  bf16x8 qfA[4], qfB[4];
  {
    const short* QrA = base + (size_t)qrowA * 2048;
    const short* QrB = QrA + 32 * 2048;
#pragma unroll
    for (int ds = 0; ds < 4; ds++) {
      qfA[ds] = *(const bf16x8*)(QrA + ds * 16 + hi * 8);
      qfB[ds] = *(const bf16x8*)(QrB + ds * 16 + hi * 8);
    }
  }

  const int krow = ln >> 3;
  const int kcol = ((ln & 7) ^ (ln >> 3)) * 8;   // pre-swizzled source col (shorts)

  float lA = 0.f, lB = 0.f;
  f32x16 oA0 = {}, oA1 = {}, oB0 = {}, oB1 = {};

#define STAGE(t, s)                                                              \
  {                                                                              \
    _Pragma("unroll")                                                            \
    for (int rd = 0; rd < 2; rd++) {                                             \
      const int r8 = 16 * wv + 8 * rd + krow;                                    \
      gload_lds16(Kg + (size_t)((t) * 64 + r8) * 2048 + kcol,                    \
                  (char*)Ks[s] + (2 * wv + rd) * 1024);                          \
      gload_lds16(Vg + (size_t)r8 * 2048 + (t) * 64 + kcol,                      \
                  (char*)Vt[s] + (2 * wv + rd) * 1024);                          \
    }                                                                            \
  }

  STAGE(0, 0);
  __syncthreads();

  for (int t = 0; t < 32; t++) {
    const int s = t & 1;
    if (t < 31) STAGE(t + 1, s ^ 1);   // prefetch next tile (drained by end syncthreads)

    // S^T = K Q^T for both q-sets; each ka read feeds 2 MFMAs
    f32x16 cA0 = {}, cA1 = {}, cB0 = {}, cB1 = {};
    const char* Kb = (const char*)Ks[s];
    __builtin_amdgcn_s_setprio(1);
#pragma unroll
    for (int ds = 0; ds < 4; ds++) {
      const int cp = (ds * 2 + hi) ^ (lq & 7);
      bf16x8 ka0 = *(const bf16x8*)(Kb + lq * 128 + cp * 16);
      bf16x8 ka1 = *(const bf16x8*)(Kb + (32 + lq) * 128 + cp * 16);
      cA0 = __builtin_amdgcn_mfma_f32_32x32x16_bf16(ka0, qfA[ds], cA0, 0, 0, 0);
      cB0 = __builtin_amdgcn_mfma_f32_32x32x16_bf16(ka0, qfB[ds], cB0, 0, 0, 0);
      cA1 = __builtin_amdgcn_mfma_f32_32x32x16_bf16(ka1, qfA[ds], cA1, 0, 0, 0);
      cB1 = __builtin_amdgcn_mfma_f32_32x32x16_bf16(ka1, qfB[ds], cB1, 0, 0, 0);
    }
    __builtin_amdgcn_s_setprio(0);

    // static-max softmax: p = exp2(s) (2^m cancels in O/l)
#pragma unroll
    for (int r = 0; r < 16; r++) cA0[r] = __builtin_amdgcn_exp2f(cA0[r]);
#pragma unroll
    for (int r = 0; r < 16; r++) cA1[r] = __builtin_amdgcn_exp2f(cA1[r]);
#pragma unroll
    for (int r = 0; r < 16; r++) cB0[r] = __builtin_amdgcn_exp2f(cB0[r]);
#pragma unroll
    for (int r = 0; r < 16; r++) cB1[r] = __builtin_amdgcn_exp2f(cB1[r]);
    {
      float sa[8], sb[8];
#pragma unroll
      for (int r = 0; r < 8; r++) {
        sa[r] = (cA0[2 * r] + cA0[2 * r + 1]) + (cA1[2 * r] + cA1[2 * r + 1]);
        sb[r] = (cB0[2 * r] + cB0[2 * r + 1]) + (cB1[2 * r] + cB1[2 * r + 1]);
      }
#pragma unroll
      for (int r = 0; r < 4; r++) { sa[r] += sa[r + 4]; sb[r] += sb[r + 4]; }
      lA += (sa[0] + sa[1]) + (sa[2] + sa[3]);
      lB += (sb[0] + sb[1]) + (sb[2] + sb[3]);
    }

    // T12: P^T B-fragments in-register for both q-sets
    bf16x8 paA[4], paB[4];
#pragma unroll
    for (int cs = 0; cs < 2; cs++) {
      const f32x16& pA = cs ? cA1 : cA0;
      const f32x16& pB = cs ? cB1 : cB0;
#pragma unroll
      for (int ksl = 0; ksl < 2; ksl++) {
        {
          unsigned A0 = cvtpk(pA[8 * ksl + 0], pA[8 * ksl + 1]);
          unsigned A1 = cvtpk(pA[8 * ksl + 2], pA[8 * ksl + 3]);
          unsigned B0 = cvtpk(pA[8 * ksl + 4], pA[8 * ksl + 5]);
          unsigned B1 = cvtpk(pA[8 * ksl + 6], pA[8 * ksl + 7]);
          swap32u(A0, B0);
          swap32u(A1, B1);
          union { unsigned u[4]; bf16x8 v; } tmp;
          tmp.u[0] = A0; tmp.u[1] = A1; tmp.u[2] = B0; tmp.u[3] = B1;
          paA[cs * 2 + ksl] = tmp.v;
        }
        {
          unsigned A0 = cvtpk(pB[8 * ksl + 0], pB[8 * ksl + 1]);
          unsigned A1 = cvtpk(pB[8 * ksl + 2], pB[8 * ksl + 3]);
          unsigned B0 = cvtpk(pB[8 * ksl + 4], pB[8 * ksl + 5]);
          unsigned B1 = cvtpk(pB[8 * ksl + 6], pB[8 * ksl + 7]);
          swap32u(A0, B0);
          swap32u(A1, B1);
          union { unsigned u[4]; bf16x8 v; } tmp;
          tmp.u[0] = A0; tmp.u[1] = A1; tmp.u[2] = B0; tmp.u[3] = B1;
          paB[cs * 2 + ksl] = tmp.v;
        }
      }
    }

    // O^T += V^T P^T; each va read feeds 2 MFMAs
    const char* Vb = (const char*)Vt[s];
    __builtin_amdgcn_s_setprio(1);
#pragma unroll
    for (int ks = 0; ks < 4; ks++) {
      const int cp = (ks * 2 + hi) ^ (lq & 7);
      bf16x8 va0 = *(const bf16x8*)(Vb + lq * 128 + cp * 16);
      bf16x8 va1 = *(const bf16x8*)(Vb + (32 + lq) * 128 + cp * 16);
      oA0 = __builtin_amdgcn_mfma_f32_32x32x16_bf16(va0, paA[ks], oA0, 0, 0, 0);
      oB0 = __builtin_amdgcn_mfma_f32_32x32x16_bf16(va0, paB[ks], oB0, 0, 0, 0);
      oA1 = __builtin_amdgcn_mfma_f32_32x32x16_bf16(va1, paA[ks], oA1, 0, 0, 0);
      oB1 = __builtin_amdgcn_mfma_f32_32x32x16_bf16(va1, paB[ks], oB1, 0, 0, 0);
    }
    __builtin_amdgcn_s_setprio(0);

    __syncthreads();
  }
#undef STAGE

  // epilogue: both q-sets
  lA += __shfl_xor(lA, 32);
  lB += __shfl_xor(lB, 32);
  const float invA = __builtin_amdgcn_rcpf(lA);
  const float invB = __builtin_amdgcn_rcpf(lB);
  short* ArA = AO + ((size_t)(b * 2048) + qrowA) * 1024 + h * 64;
  short* ArB = ArA + 32 * 1024;
#pragma unroll
  for (int dt = 0; dt < 2; dt++) {
    const f32x16& oa = dt ? oA1 : oA0;
    const f32x16& ob = dt ? oB1 : oB0;
#pragma unroll
    for (int g = 0; g < 4; g++) {
      bf16x4 wa, wb;
#pragma unroll
      for (int i = 0; i < 4; i++) {
        wa[i] = f2bf(oa[4 * g + i] * invA);
        wb[i] = f2bf(ob[4 * g + i] * invB);
      }
      *(bf16x4*)(ArA + dt * 32 + 8 * g + 4 * hi) = wa;
      *(bf16x4*)(ArB + dt * 32 + 8 * g + 4 * hi) = wb;
    }
  }
}

// ---------------- launch ----------------
extern "C" void kernel_launch(void* const* d_in, const int* in_sizes, int n_in,
                              void* d_out, int out_size, void* d_ws, size_t ws_size,
                              hipStream_t stream) {
  const float* x = (const float*)d_in[0];       // [2,2048,1024]
  const float* w_qkv = (const float*)d_in[1];   // [3072,1024]
  const float* w_proj = (const float*)d_in[2];  // [1024,1024]
  const float* b_proj = (const float*)d_in[3];  // [1024]
  float* out = (float*)d_out;                   // [2,2048,1024] fp32

  char* ws = (char*)d_ws;
  short* Xb  = (short*)(ws + 0);                 //  8 MB  [4096][1024]
  short* Wq  = (short*)(ws + 8388608);           //  6 MB  [3072][1024]
  short* Wp  = (short*)(ws + 14680064);          //  2 MB  [1024][1024]
  short* QK  = (short*)(ws + 16777216);          // 16 MB  [4096][2048]
  short* Vtg = (short*)(ws + 33554432);          //  8 MB  [32*64][2048]
  short* AO  = (short*)(ws + 41943040);          //  8 MB  [4096][1024]

  cvt_all<<<4096, 256, 0, stream>>>(x, w_qkv, w_proj, Xb, Wq, Wp);

  // qkv GEMM: 768 blocks, XCD owns 3 B-col panels (768KB L2-resident)
  gemm_db<0, 1, 3><<<dim3(768), 256, 0, stream>>>(Xb, Wq, QK, Vtg, nullptr,
                                                  1024, QSCALE, 4096, 3072, 1024);

  attn_fwd<<<dim3(256), 256, 0, stream>>>(QK, Vtg, AO);

  // proj GEMM: 256 blocks, XCD owns 1 B-col panel (256KB L2-resident)
  gemm_db<1, 0, 1><<<dim3(256), 256, 0, stream>>>(AO, Wp, out, nullptr, b_proj,
                                                  0, 1.0f, 4096, 1024, 1024);
}

// Round 14
// 103.839 us; speedup vs baseline: 1.0463x; 1.0463x over previous
//
#include <hip/hip_runtime.h>
#include <hip/hip_bf16.h>
#include <stdint.h>

typedef __attribute__((ext_vector_type(4))) float f32x4;
typedef __attribute__((ext_vector_type(16))) float f32x16;
typedef __attribute__((ext_vector_type(8))) short bf16x8;
typedef __attribute__((ext_vector_type(4))) short bf16x4;
typedef unsigned short ushort_t;

#define QSCALE 0.18033688f   // 0.125 * log2(e): softmax runs in exp2 domain

__device__ inline short f2bf(float f) {
  unsigned u = __builtin_bit_cast(unsigned, f);
  u += 0x7fffu + ((u >> 16) & 1u);   // RNE
  return (short)(u >> 16);
}

__device__ inline void gload_lds16(const void* g, void* l) {
  __builtin_amdgcn_global_load_lds(
      (const __attribute__((address_space(1))) void*)g,
      (__attribute__((address_space(3))) void*)l, 16, 0, 0);
}

__device__ inline unsigned cvtpk(float a, float b) {
  unsigned r;
  asm("v_cvt_pk_bf16_f32 %0, %1, %2" : "=v"(r) : "v"(a), "v"(b));
  return r;
}

__device__ inline void swap32u(unsigned& a, unsigned& b) {
  asm("v_permlane32_swap_b32 %0, %1" : "+v"(a), "+v"(b));
}

// ---------------- fused fp32 -> bf16 convert (x, w_qkv, w_proj) ----------------
__global__ __launch_bounds__(256) void cvt_all(const float* __restrict__ x,
                                               const float* __restrict__ wq,
                                               const float* __restrict__ wp,
                                               short* __restrict__ Xb,
                                               short* __restrict__ Wq,
                                               short* __restrict__ Wp) {
  int i = blockIdx.x * 256 + threadIdx.x;   // vec8 index, total 1048576
  const float* s;
  short* d;
  int off;
  if (i < 524288)       { s = x;  d = Xb; off = i; }
  else if (i < 917504)  { s = wq; d = Wq; off = i - 524288; }
  else                  { s = wp; d = Wp; off = i - 917504; }
  const float4* sv = (const float4*)s;
  float4 a = sv[2 * off], b = sv[2 * off + 1];
  bf16x8 o;
  o[0] = f2bf(a.x); o[1] = f2bf(a.y); o[2] = f2bf(a.z); o[3] = f2bf(a.w);
  o[4] = f2bf(b.x); o[5] = f2bf(b.y); o[6] = f2bf(b.z); o[7] = f2bf(b.w);
  ((bf16x8*)d)[off] = o;
}

// ---------------- 128x128 BK=64 double-buffer counted-vmcnt GEMM: C = A * B^T ----------------
// T1 XCD swizzle: 1-D grid, xcd = id&7 owns BXPX consecutive B-column panels.
// SPLITV=1 (qkv): cols<2048 -> QK (q pre-scaled); cols>=2048 -> Vtg via LDS transpose.
template <int F32OUT, int SPLITV, int BXPX>
__global__ __launch_bounds__(256, 2) void gemm_db(const short* __restrict__ A,
                                                  const short* __restrict__ B,
                                                  void* __restrict__ Cv,
                                                  short* __restrict__ Vtg,
                                                  const float* __restrict__ bias,
                                                  int scale_cols, float scale_val,
                                                  int M, int N, int K) {
  __shared__ char smem[65536];
  short* Ab0 = (short*)smem;                 // [2][128*64]
  short* Bb0 = (short*)(smem + 32768);       // [2][128*64]
  const int tid = threadIdx.x, wv = tid >> 6, ln = tid & 63;
  const int wm = wv >> 1, wn = wv & 1;       // 2x2 waves, 64x64 each
  const int id = blockIdx.x;
  const int xcd = id & 7, local = id >> 3;
  const int bx = xcd * BXPX + local % BXPX;
  const int by = local / BXPX;
  const int bn0 = bx * 128, bm0 = by * 128;
  const int nt = K >> 6;                     // BK = 64

  const int srow = ln >> 3;
  const int scol = ((ln & 7) ^ (ln >> 3)) * 8;
  const int fln = ln & 15;
  const int fk = ln >> 4;

  f32x4 acc[4][4] = {};

  auto stage = [&](int t, int s) {
    const size_t k0 = (size_t)t << 6;
#pragma unroll
    for (int rd = 0; rd < 4; rd++) {
      const int ch = 4 * wv + rd;
      gload_lds16(A + (size_t)(bm0 + ch * 8 + srow) * K + k0 + scol,
                  (char*)(Ab0 + s * 8192) + ch * 1024);
      gload_lds16(B + (size_t)(bn0 + ch * 8 + srow) * K + k0 + scol,
                  (char*)(Bb0 + s * 8192) + ch * 1024);
    }
  };

  stage(0, 0);
  stage(1, 1);
  asm volatile("s_waitcnt vmcnt(8)" ::: "memory");
  __builtin_amdgcn_s_barrier();
  __builtin_amdgcn_sched_barrier(0);

  for (int t = 0; t < nt; t++) {
    const int s = t & 1;
    const char* Ap = (const char*)(Ab0 + s * 8192);
    const char* Bp = (const char*)(Bb0 + s * 8192);

    bf16x8 af[4][2], bf[4][2];
#pragma unroll
    for (int m = 0; m < 4; m++) {
      const int R = wm * 64 + m * 16 + fln;
#pragma unroll
      for (int kk = 0; kk < 2; kk++)
        af[m][kk] = *(const bf16x8*)(Ap + R * 128 + ((((kk << 2) | fk) ^ (R & 7)) << 4));
    }
#pragma unroll
    for (int n = 0; n < 4; n++) {
      const int R = wn * 64 + n * 16 + fln;
#pragma unroll
      for (int kk = 0; kk < 2; kk++)
        bf[n][kk] = *(const bf16x8*)(Bp + R * 128 + ((((kk << 2) | fk) ^ (R & 7)) << 4));
    }

    __builtin_amdgcn_s_setprio(1);
#pragma unroll
    for (int kk = 0; kk < 2; kk++)
#pragma unroll
      for (int m = 0; m < 4; m++)
#pragma unroll
        for (int n = 0; n < 4; n++)
          acc[m][n] = __builtin_amdgcn_mfma_f32_16x16x32_bf16(af[m][kk], bf[n][kk], acc[m][n], 0, 0, 0);
    __builtin_amdgcn_s_setprio(0);

    if (t + 1 < nt) {
      __builtin_amdgcn_s_barrier();
      if (t + 2 < nt) {
        stage(t + 2, s);
        asm volatile("s_waitcnt vmcnt(8)" ::: "memory");
      } else {
        asm volatile("s_waitcnt vmcnt(0)" ::: "memory");
      }
      __builtin_amdgcn_s_barrier();
      __builtin_amdgcn_sched_barrier(0);
    }
  }

  // ---------- epilogue ----------
  if constexpr (SPLITV) {
    if (bn0 >= 2048) {
      __syncthreads();
      short* Vl = (short*)smem;   // [128 f][136 tok]
#pragma unroll
      for (int m = 0; m < 4; m++) {
        const int tok0 = wm * 64 + m * 16 + fk * 4;
#pragma unroll
        for (int n = 0; n < 4; n++) {
          const int f_loc = wn * 64 + n * 16 + fln;
          bf16x4 w;
#pragma unroll
          for (int j = 0; j < 4; j++) w[j] = f2bf(acc[m][n][j]);
          *(bf16x4*)(Vl + f_loc * 136 + tok0) = w;
        }
      }
      __syncthreads();
      const int fbase = bn0 - 2048, bb = bm0 >> 11, ntok0 = bm0 & 2047;
#pragma unroll
      for (int pass = 0; pass < 8; pass++) {
        const int f_loc = wv * 32 + pass * 4 + (ln >> 4);
        const int f = fbase + f_loc;
        const int g = (bb * 16 + (f >> 6)) * 64 + (f & 63);
        bf16x8 w = *(const bf16x8*)(Vl + f_loc * 136 + (ln & 15) * 8);
        *(bf16x8*)(Vtg + (size_t)g * 2048 + ntok0 + (ln & 15) * 8) = w;
      }
      return;
    }
  }

  const int r0 = bm0 + wm * 64, c0 = bn0 + wn * 64;
  const int fg4 = fk * 4;
#pragma unroll
  for (int m = 0; m < 4; m++) {
    const int row0 = r0 + m * 16 + fg4;
#pragma unroll
    for (int n = 0; n < 4; n++) {
      const int col = c0 + n * 16 + fln;
      if constexpr (SPLITV) {
        const float sc = (col < scale_cols) ? scale_val : 1.0f;
#pragma unroll
        for (int j = 0; j < 4; j++)
          ((short*)Cv)[(size_t)(row0 + j) * 2048 + col] = f2bf(acc[m][n][j] * sc);
      } else {
#pragma unroll
        for (int j = 0; j < 4; j++) {
          float v = acc[m][n][j];
          if (col < scale_cols) v *= scale_val;
          if (F32OUT) ((float*)Cv)[(size_t)(row0 + j) * N + col] = v + bias[col];
          else        ((short*)Cv)[(size_t)(row0 + j) * N + col] = f2bf(v);
        }
      }
    }
  }
}

// ---------------- flash attention: R8 skeleton + l via matrix pipe ----------------
// QK: [4096][2048] bf16 (q pre-scaled, k at +1024). Vtg: [(b*16+h)*64+d][2048] bf16.
// Grid 512 (XCD-swizzled), 256 thr = 4 waves x 32 q-rows. 32 tiles of 64 kv.
// l[q] = sum_kv P^T[kv][q] computed as mfma(ones, pa[ks], lacc): all-ones A makes
// every output row the column-sum; lane ends with complete l[lq] (no shfl, no tree).
__global__ __launch_bounds__(256, 2) void attn_fwd(const short* __restrict__ QK,
                                                   const short* __restrict__ Vtg,
                                                   short* __restrict__ AO) {
  __shared__ short Ks[2][64 * 64];   // [kv][d], XOR-swizzled 16B chunks
  __shared__ short Vt[2][64 * 64];   // [d][kv], XOR-swizzled (staged from Vtg)
  const int tid = threadIdx.x, wv = tid >> 6, ln = tid & 63;
  const int lq = ln & 31, hi = ln >> 5;
  const int id = blockIdx.x;
  const int c = (id & 7) * 64 + (id >> 3);   // XCD swizzle: 4 heads per XCD
  const int qt = c & 15, bh = c >> 4;
  const int b = bh >> 4, h = bh & 15;
  const short* base = QK + (size_t)(b * 2048) * 2048 + h * 64;
  const short* Kg = base + 1024;
  const short* Vg = Vtg + (size_t)bh * 64 * 2048;   // rows d, cols token
  const int qrow = qt * 128 + wv * 32 + lq;

  bf16x8 qf[4];
  {
    const short* Qrow = base + (size_t)qrow * 2048;
#pragma unroll
    for (int ds = 0; ds < 4; ds++)
      qf[ds] = *(const bf16x8*)(Qrow + ds * 16 + hi * 8);
  }

  bf16x8 onesf;
#pragma unroll
  for (int i = 0; i < 8; i++) onesf[i] = (short)0x3F80;   // bf16 1.0

  const int krow = ln >> 3;
  const int kcol = ((ln & 7) ^ (ln >> 3)) * 8;   // pre-swizzled source col (shorts)

  f32x16 o0 = {}, o1 = {}, lacc = {};

#define STAGE(t, s)                                                              \
  {                                                                              \
    _Pragma("unroll")                                                            \
    for (int rd = 0; rd < 2; rd++) {                                             \
      const int r8 = 16 * wv + 8 * rd + krow;                                    \
      gload_lds16(Kg + (size_t)((t) * 64 + r8) * 2048 + kcol,                    \
                  (char*)Ks[s] + (2 * wv + rd) * 1024);                          \
      gload_lds16(Vg + (size_t)r8 * 2048 + (t) * 64 + kcol,                      \
                  (char*)Vt[s] + (2 * wv + rd) * 1024);                          \
    }                                                                            \
  }

  STAGE(0, 0);
  __syncthreads();

  for (int t = 0; t < 32; t++) {
    const int s = t & 1;
    if (t < 31) STAGE(t + 1, s ^ 1);   // prefetch next tile (drained at end barrier)

    // S^T = K Q^T (log2-domain scores; q pre-scaled by 0.125*log2e)
    f32x16 c0 = {}, c1 = {};
    const char* Kb = (const char*)Ks[s];
    __builtin_amdgcn_s_setprio(1);
#pragma unroll
    for (int ds = 0; ds < 4; ds++) {
      const int cp = (ds * 2 + hi) ^ (lq & 7);
      bf16x8 ka0 = *(const bf16x8*)(Kb + lq * 128 + cp * 16);
      bf16x8 ka1 = *(const bf16x8*)(Kb + (32 + lq) * 128 + cp * 16);
      c0 = __builtin_amdgcn_mfma_f32_32x32x16_bf16(ka0, qf[ds], c0, 0, 0, 0);
      c1 = __builtin_amdgcn_mfma_f32_32x32x16_bf16(ka1, qf[ds], c1, 0, 0, 0);
    }
    __builtin_amdgcn_s_setprio(0);

    // static-max softmax: p = exp2(s) directly (2^m cancels in O/l)
#pragma unroll
    for (int r = 0; r < 16; r++) c0[r] = __builtin_amdgcn_exp2f(c0[r]);
#pragma unroll
    for (int r = 0; r < 16; r++) c1[r] = __builtin_amdgcn_exp2f(c1[r]);

    // T12: P^T B-fragments in-register
    bf16x8 pa[4];
#pragma unroll
    for (int cs = 0; cs < 2; cs++) {
      const f32x16& p = cs ? c1 : c0;
#pragma unroll
      for (int ksl = 0; ksl < 2; ksl++) {
        unsigned A0 = cvtpk(p[8 * ksl + 0], p[8 * ksl + 1]);
        unsigned A1 = cvtpk(p[8 * ksl + 2], p[8 * ksl + 3]);
        unsigned B0 = cvtpk(p[8 * ksl + 4], p[8 * ksl + 5]);
        unsigned B1 = cvtpk(p[8 * ksl + 6], p[8 * ksl + 7]);
        swap32u(A0, B0);
        swap32u(A1, B1);
        union { unsigned u[4]; bf16x8 v; } tmp;
        tmp.u[0] = A0; tmp.u[1] = A1; tmp.u[2] = B0; tmp.u[3] = B1;
        pa[cs * 2 + ksl] = tmp.v;
      }
    }

    // O^T += V^T P^T ; l += ones P^T (column sums via matrix pipe)
    const char* Vb = (const char*)Vt[s];
    __builtin_amdgcn_s_setprio(1);
#pragma unroll
    for (int ks = 0; ks < 4; ks++) {
      const int cp = (ks * 2 + hi) ^ (lq & 7);
      bf16x8 va0 = *(const bf16x8*)(Vb + lq * 128 + cp * 16);
      bf16x8 va1 = *(const bf16x8*)(Vb + (32 + lq) * 128 + cp * 16);
      o0 = __builtin_amdgcn_mfma_f32_32x32x16_bf16(va0, pa[ks], o0, 0, 0, 0);
      o1 = __builtin_amdgcn_mfma_f32_32x32x16_bf16(va1, pa[ks], o1, 0, 0, 0);
      lacc = __builtin_amdgcn_mfma_f32_32x32x16_bf16(onesf, pa[ks], lacc, 0, 0, 0);
    }
    __builtin_amdgcn_s_setprio(0);

    __syncthreads();
  }
#undef STAGE

  // epilogue: lane already holds full l[lq] in every lacc reg
  const float inv = __builtin_amdgcn_rcpf(lacc[0]);
  short* Arow = AO + ((size_t)(b * 2048) + qrow) * 1024 + h * 64;
#pragma unroll
  for (int dt = 0; dt < 2; dt++) {
    const f32x16& o = dt ? o1 : o0;
#pragma unroll
    for (int g = 0; g < 4; g++) {
      bf16x4 w;
#pragma unroll
      for (int i = 0; i < 4; i++) w[i] = f2bf(o[4 * g + i] * inv);
      *(bf16x4*)(Arow + dt * 32 + 8 * g + 4 * hi) = w;
    }
  }
}

// ---------------- launch ----------------
extern "C" void kernel_launch(void* const* d_in, const int* in_sizes, int n_in,
                              void* d_out, int out_size, void* d_ws, size_t ws_size,
                              hipStream_t stream) {
  const float* x = (const float*)d_in[0];       // [2,2048,1024]
  const float* w_qkv = (const float*)d_in[1];   // [3072,1024]
  const float* w_proj = (const float*)d_in[2];  // [1024,1024]
  const float* b_proj = (const float*)d_in[3];  // [1024]
  float* out = (float*)d_out;                   // [2,2048,1024] fp32

  char* ws = (char*)d_ws;
  short* Xb  = (short*)(ws + 0);                 //  8 MB  [4096][1024]
  short* Wq  = (short*)(ws + 8388608);           //  6 MB  [3072][1024]
  short* Wp  = (short*)(ws + 14680064);          //  2 MB  [1024][1024]
  short* QK  = (short*)(ws + 16777216);          // 16 MB  [4096][2048]
  short* Vtg = (short*)(ws + 33554432);          //  8 MB  [32*64][2048]
  short* AO  = (short*)(ws + 41943040);          //  8 MB  [4096][1024]

  cvt_all<<<4096, 256, 0, stream>>>(x, w_qkv, w_proj, Xb, Wq, Wp);

  // qkv GEMM: 768 blocks, XCD owns 3 B-col panels (768KB L2-resident)
  gemm_db<0, 1, 3><<<dim3(768), 256, 0, stream>>>(Xb, Wq, QK, Vtg, nullptr,
                                                  1024, QSCALE, 4096, 3072, 1024);

  attn_fwd<<<dim3(512), 256, 0, stream>>>(QK, Vtg, AO);

  // proj GEMM: 256 blocks, XCD owns 1 B-col panel (256KB L2-resident)
  gemm_db<1, 0, 1><<<dim3(256), 256, 0, stream>>>(AO, Wp, out, nullptr, b_proj,
                                                  0, 1.0f, 4096, 1024, 1024);
}

// Round 15
// 103.463 us; speedup vs baseline: 1.0501x; 1.0036x over previous
//
#include <hip/hip_runtime.h>
#include <hip/hip_bf16.h>
#include <stdint.h>

typedef __attribute__((ext_vector_type(4))) float f32x4;
typedef __attribute__((ext_vector_type(16))) float f32x16;
typedef __attribute__((ext_vector_type(8))) short bf16x8;
typedef __attribute__((ext_vector_type(4))) short bf16x4;
typedef unsigned short ushort_t;

#define QSCALE 0.18033688f   // 0.125 * log2(e): softmax runs in exp2 domain

__device__ inline short f2bf(float f) {
  unsigned u = __builtin_bit_cast(unsigned, f);
  u += 0x7fffu + ((u >> 16) & 1u);   // RNE
  return (short)(u >> 16);
}

__device__ inline void gload_lds16(const void* g, void* l) {
  __builtin_amdgcn_global_load_lds(
      (const __attribute__((address_space(1))) void*)g,
      (__attribute__((address_space(3))) void*)l, 16, 0, 0);
}

__device__ inline unsigned cvtpk(float a, float b) {
  unsigned r;
  asm("v_cvt_pk_bf16_f32 %0, %1, %2" : "=v"(r) : "v"(a), "v"(b));
  return r;
}

__device__ inline void swap32u(unsigned& a, unsigned& b) {
  asm("v_permlane32_swap_b32 %0, %1" : "+v"(a), "+v"(b));
}

// ---------------- fused fp32 -> bf16 convert (x, w_qkv, w_proj) ----------------
__global__ __launch_bounds__(256) void cvt_all(const float* __restrict__ x,
                                               const float* __restrict__ wq,
                                               const float* __restrict__ wp,
                                               short* __restrict__ Xb,
                                               short* __restrict__ Wq,
                                               short* __restrict__ Wp) {
  int i = blockIdx.x * 256 + threadIdx.x;   // vec8 index, total 1048576
  const float* s;
  short* d;
  int off;
  if (i < 524288)       { s = x;  d = Xb; off = i; }
  else if (i < 917504)  { s = wq; d = Wq; off = i - 524288; }
  else                  { s = wp; d = Wp; off = i - 917504; }
  const float4* sv = (const float4*)s;
  float4 a = sv[2 * off], b = sv[2 * off + 1];
  bf16x8 o;
  o[0] = f2bf(a.x); o[1] = f2bf(a.y); o[2] = f2bf(a.z); o[3] = f2bf(a.w);
  o[4] = f2bf(b.x); o[5] = f2bf(b.y); o[6] = f2bf(b.z); o[7] = f2bf(b.w);
  ((bf16x8*)d)[off] = o;
}

// ---------------- 128x128 BK=64 double-buffer counted-vmcnt GEMM: C = A * B^T ----------------
// T1 XCD swizzle: 1-D grid, xcd = id&7 owns BXPX consecutive B-column panels.
// SPLITV=1 (qkv): cols<2048 -> QK (q pre-scaled); cols>=2048 -> Vtg via LDS transpose.
template <int F32OUT, int SPLITV, int BXPX>
__global__ __launch_bounds__(256, 2) void gemm_db(const short* __restrict__ A,
                                                  const short* __restrict__ B,
                                                  void* __restrict__ Cv,
                                                  short* __restrict__ Vtg,
                                                  const float* __restrict__ bias,
                                                  int scale_cols, float scale_val,
                                                  int M, int N, int K) {
  __shared__ char smem[65536];
  short* Ab0 = (short*)smem;                 // [2][128*64]
  short* Bb0 = (short*)(smem + 32768);       // [2][128*64]
  const int tid = threadIdx.x, wv = tid >> 6, ln = tid & 63;
  const int wm = wv >> 1, wn = wv & 1;       // 2x2 waves, 64x64 each
  const int id = blockIdx.x;
  const int xcd = id & 7, local = id >> 3;
  const int bx = xcd * BXPX + local % BXPX;
  const int by = local / BXPX;
  const int bn0 = bx * 128, bm0 = by * 128;
  const int nt = K >> 6;                     // BK = 64

  const int srow = ln >> 3;
  const int scol = ((ln & 7) ^ (ln >> 3)) * 8;
  const int fln = ln & 15;
  const int fk = ln >> 4;

  f32x4 acc[4][4] = {};

  auto stage = [&](int t, int s) {
    const size_t k0 = (size_t)t << 6;
#pragma unroll
    for (int rd = 0; rd < 4; rd++) {
      const int ch = 4 * wv + rd;
      gload_lds16(A + (size_t)(bm0 + ch * 8 + srow) * K + k0 + scol,
                  (char*)(Ab0 + s * 8192) + ch * 1024);
      gload_lds16(B + (size_t)(bn0 + ch * 8 + srow) * K + k0 + scol,
                  (char*)(Bb0 + s * 8192) + ch * 1024);
    }
  };

  stage(0, 0);
  stage(1, 1);
  asm volatile("s_waitcnt vmcnt(8)" ::: "memory");
  __builtin_amdgcn_s_barrier();
  __builtin_amdgcn_sched_barrier(0);

  for (int t = 0; t < nt; t++) {
    const int s = t & 1;
    const char* Ap = (const char*)(Ab0 + s * 8192);
    const char* Bp = (const char*)(Bb0 + s * 8192);

    bf16x8 af[4][2], bf[4][2];
#pragma unroll
    for (int m = 0; m < 4; m++) {
      const int R = wm * 64 + m * 16 + fln;
#pragma unroll
      for (int kk = 0; kk < 2; kk++)
        af[m][kk] = *(const bf16x8*)(Ap + R * 128 + ((((kk << 2) | fk) ^ (R & 7)) << 4));
    }
#pragma unroll
    for (int n = 0; n < 4; n++) {
      const int R = wn * 64 + n * 16 + fln;
#pragma unroll
      for (int kk = 0; kk < 2; kk++)
        bf[n][kk] = *(const bf16x8*)(Bp + R * 128 + ((((kk << 2) | fk) ^ (R & 7)) << 4));
    }

    __builtin_amdgcn_s_setprio(1);
#pragma unroll
    for (int kk = 0; kk < 2; kk++)
#pragma unroll
      for (int m = 0; m < 4; m++)
#pragma unroll
        for (int n = 0; n < 4; n++)
          acc[m][n] = __builtin_amdgcn_mfma_f32_16x16x32_bf16(af[m][kk], bf[n][kk], acc[m][n], 0, 0, 0);
    __builtin_amdgcn_s_setprio(0);

    if (t + 1 < nt) {
      __builtin_amdgcn_s_barrier();
      if (t + 2 < nt) {
        stage(t + 2, s);
        asm volatile("s_waitcnt vmcnt(8)" ::: "memory");
      } else {
        asm volatile("s_waitcnt vmcnt(0)" ::: "memory");
      }
      __builtin_amdgcn_s_barrier();
      __builtin_amdgcn_sched_barrier(0);
    }
  }

  // ---------- epilogue ----------
  if constexpr (SPLITV) {
    if (bn0 >= 2048) {
      __syncthreads();
      short* Vl = (short*)smem;   // [128 f][136 tok]
#pragma unroll
      for (int m = 0; m < 4; m++) {
        const int tok0 = wm * 64 + m * 16 + fk * 4;
#pragma unroll
        for (int n = 0; n < 4; n++) {
          const int f_loc = wn * 64 + n * 16 + fln;
          bf16x4 w;
#pragma unroll
          for (int j = 0; j < 4; j++) w[j] = f2bf(acc[m][n][j]);
          *(bf16x4*)(Vl + f_loc * 136 + tok0) = w;
        }
      }
      __syncthreads();
      const int fbase = bn0 - 2048, bb = bm0 >> 11, ntok0 = bm0 & 2047;
#pragma unroll
      for (int pass = 0; pass < 8; pass++) {
        const int f_loc = wv * 32 + pass * 4 + (ln >> 4);
        const int f = fbase + f_loc;
        const int g = (bb * 16 + (f >> 6)) * 64 + (f & 63);
        bf16x8 w = *(const bf16x8*)(Vl + f_loc * 136 + (ln & 15) * 8);
        *(bf16x8*)(Vtg + (size_t)g * 2048 + ntok0 + (ln & 15) * 8) = w;
      }
      return;
    }
  }

  const int r0 = bm0 + wm * 64, c0 = bn0 + wn * 64;
  const int fg4 = fk * 4;
#pragma unroll
  for (int m = 0; m < 4; m++) {
    const int row0 = r0 + m * 16 + fg4;
#pragma unroll
    for (int n = 0; n < 4; n++) {
      const int col = c0 + n * 16 + fln;
      if constexpr (SPLITV) {
        const float sc = (col < scale_cols) ? scale_val : 1.0f;
#pragma unroll
        for (int j = 0; j < 4; j++)
          ((short*)Cv)[(size_t)(row0 + j) * 2048 + col] = f2bf(acc[m][n][j] * sc);
      } else {
#pragma unroll
        for (int j = 0; j < 4; j++) {
          float v = acc[m][n][j];
          if (col < scale_cols) v *= scale_val;
          if (F32OUT) ((float*)Cv)[(size_t)(row0 + j) * N + col] = v + bias[col];
          else        ((short*)Cv)[(size_t)(row0 + j) * N + col] = f2bf(v);
        }
      }
    }
  }
}

// ---------------- flash attention: T15 double-pipeline (QK(t) overlaps SM+PV(t-1)) ----------------
// QK: [4096][2048] bf16 (q pre-scaled, k at +1024). Vtg: [(b*16+h)*64+d][2048] bf16.
// Grid 512 (XCD-swizzled), 256 thr = 4 waves x 32 q-rows. 32 tiles of 64 kv, 3-buffer LDS.
// Phase t: STAGE(t+1) | QK(t) MFMAs | exp2/cvtpk/PV of tile t-1 (separate pipes overlap).
// l via matrix pipe: mfma(ones, pa, lacc) -> lane holds full l[lq].
__global__ __launch_bounds__(256, 2) void attn_fwd(const short* __restrict__ QK,
                                                   const short* __restrict__ Vtg,
                                                   short* __restrict__ AO) {
  __shared__ short Ks[3][64 * 64];   // [kv][d], XOR-swizzled 16B chunks
  __shared__ short Vt[3][64 * 64];   // [d][kv], XOR-swizzled (staged from Vtg)
  const int tid = threadIdx.x, wv = tid >> 6, ln = tid & 63;
  const int lq = ln & 31, hi = ln >> 5;
  const int id = blockIdx.x;
  const int c = (id & 7) * 64 + (id >> 3);   // XCD swizzle: 4 heads per XCD
  const int qt = c & 15, bh = c >> 4;
  const int b = bh >> 4, h = bh & 15;
  const short* base = QK + (size_t)(b * 2048) * 2048 + h * 64;
  const short* Kg = base + 1024;
  const short* Vg = Vtg + (size_t)bh * 64 * 2048;   // rows d, cols token
  const int qrow = qt * 128 + wv * 32 + lq;

  bf16x8 qf[4];
  {
    const short* Qrow = base + (size_t)qrow * 2048;
#pragma unroll
    for (int ds = 0; ds < 4; ds++)
      qf[ds] = *(const bf16x8*)(Qrow + ds * 16 + hi * 8);
  }

  bf16x8 onesf;
#pragma unroll
  for (int i = 0; i < 8; i++) onesf[i] = (short)0x3F80;   // bf16 1.0

  const int krow = ln >> 3;
  const int kcol = ((ln & 7) ^ (ln >> 3)) * 8;   // pre-swizzled source col (shorts)

  f32x16 o0 = {}, o1 = {}, lacc = {};
  f32x16 cp0, cp1;   // saved raw scores of tile t-1 (softmax finished one phase late)

#define STAGE(t, s)                                                              \
  {                                                                              \
    _Pragma("unroll")                                                            \
    for (int rd = 0; rd < 2; rd++) {                                             \
      const int r8 = 16 * wv + 8 * rd + krow;                                    \
      gload_lds16(Kg + (size_t)((t) * 64 + r8) * 2048 + kcol,                    \
                  (char*)Ks[s] + (2 * wv + rd) * 1024);                          \
      gload_lds16(Vg + (size_t)r8 * 2048 + (t) * 64 + kcol,                      \
                  (char*)Vt[s] + (2 * wv + rd) * 1024);                          \
    }                                                                            \
  }

// softmax-finish + PV for the tile whose raw scores are in cp0/cp1, V in Vt[vs]
#define FINISH_PV(vs)                                                            \
  {                                                                              \
    _Pragma("unroll")                                                            \
    for (int r = 0; r < 16; r++) cp0[r] = __builtin_amdgcn_exp2f(cp0[r]);        \
    _Pragma("unroll")                                                            \
    for (int r = 0; r < 16; r++) cp1[r] = __builtin_amdgcn_exp2f(cp1[r]);        \
    bf16x8 pa[4];                                                                \
    _Pragma("unroll")                                                            \
    for (int cs = 0; cs < 2; cs++) {                                             \
      const f32x16& p = cs ? cp1 : cp0;                                          \
      _Pragma("unroll")                                                          \
      for (int ksl = 0; ksl < 2; ksl++) {                                        \
        unsigned A0 = cvtpk(p[8 * ksl + 0], p[8 * ksl + 1]);                     \
        unsigned A1 = cvtpk(p[8 * ksl + 2], p[8 * ksl + 3]);                     \
        unsigned B0 = cvtpk(p[8 * ksl + 4], p[8 * ksl + 5]);                     \
        unsigned B1 = cvtpk(p[8 * ksl + 6], p[8 * ksl + 7]);                     \
        swap32u(A0, B0);                                                         \
        swap32u(A1, B1);                                                         \
        union { unsigned u[4]; bf16x8 v; } tmp;                                  \
        tmp.u[0] = A0; tmp.u[1] = A1; tmp.u[2] = B0; tmp.u[3] = B1;              \
        pa[cs * 2 + ksl] = tmp.v;                                                \
      }                                                                          \
    }                                                                            \
    const char* Vb = (const char*)Vt[vs];                                        \
    _Pragma("unroll")                                                            \
    for (int ks = 0; ks < 4; ks++) {                                             \
      const int cp = (ks * 2 + hi) ^ (lq & 7);                                   \
      bf16x8 va0 = *(const bf16x8*)(Vb + lq * 128 + cp * 16);                    \
      bf16x8 va1 = *(const bf16x8*)(Vb + (32 + lq) * 128 + cp * 16);             \
      o0 = __builtin_amdgcn_mfma_f32_32x32x16_bf16(va0, pa[ks], o0, 0, 0, 0);    \
      o1 = __builtin_amdgcn_mfma_f32_32x32x16_bf16(va1, pa[ks], o1, 0, 0, 0);    \
      lacc = __builtin_amdgcn_mfma_f32_32x32x16_bf16(onesf, pa[ks], lacc, 0, 0, 0); \
    }                                                                            \
  }

  STAGE(0, 0);
  __syncthreads();

  for (int t = 0; t < 32; t++) {
    if (t < 31) STAGE(t + 1, (t + 1) % 3);   // prefetch (drained at end barrier)

    // QK(t): raw log2-domain scores (q pre-scaled by 0.125*log2e)
    f32x16 c0 = {}, c1 = {};
    const char* Kb = (const char*)Ks[t % 3];
    __builtin_amdgcn_s_setprio(1);
#pragma unroll
    for (int ds = 0; ds < 4; ds++) {
      const int cp = (ds * 2 + hi) ^ (lq & 7);
      bf16x8 ka0 = *(const bf16x8*)(Kb + lq * 128 + cp * 16);
      bf16x8 ka1 = *(const bf16x8*)(Kb + (32 + lq) * 128 + cp * 16);
      c0 = __builtin_amdgcn_mfma_f32_32x32x16_bf16(ka0, qf[ds], c0, 0, 0, 0);
      c1 = __builtin_amdgcn_mfma_f32_32x32x16_bf16(ka1, qf[ds], c1, 0, 0, 0);
    }
    __builtin_amdgcn_s_setprio(0);

    // softmax-finish + PV of tile t-1 (VALU exp2/cvtpk overlaps the QK MFMAs above)
    if (t > 0) {
      FINISH_PV((t - 1) % 3);
    }

    cp0 = c0;   // save raw scores for next phase's finish
    cp1 = c1;
    __syncthreads();
  }
  // epilogue: finish tile 31 (V in Vt[31%3])
  FINISH_PV(31 % 3);
#undef FINISH_PV
#undef STAGE

  // lane already holds full l[lq] in every lacc reg
  const float inv = __builtin_amdgcn_rcpf(lacc[0]);
  short* Arow = AO + ((size_t)(b * 2048) + qrow) * 1024 + h * 64;
#pragma unroll
  for (int dt = 0; dt < 2; dt++) {
    const f32x16& o = dt ? o1 : o0;
#pragma unroll
    for (int g = 0; g < 4; g++) {
      bf16x4 w;
#pragma unroll
      for (int i = 0; i < 4; i++) w[i] = f2bf(o[4 * g + i] * inv);
      *(bf16x4*)(Arow + dt * 32 + 8 * g + 4 * hi) = w;
    }
  }
}

// ---------------- launch ----------------
extern "C" void kernel_launch(void* const* d_in, const int* in_sizes, int n_in,
                              void* d_out, int out_size, void* d_ws, size_t ws_size,
                              hipStream_t stream) {
  const float* x = (const float*)d_in[0];       // [2,2048,1024]
  const float* w_qkv = (const float*)d_in[1];   // [3072,1024]
  const float* w_proj = (const float*)d_in[2];  // [1024,1024]
  const float* b_proj = (const float*)d_in[3];  // [1024]
  float* out = (float*)d_out;                   // [2,2048,1024] fp32

  char* ws = (char*)d_ws;
  short* Xb  = (short*)(ws + 0);                 //  8 MB  [4096][1024]
  short* Wq  = (short*)(ws + 8388608);           //  6 MB  [3072][1024]
  short* Wp  = (short*)(ws + 14680064);          //  2 MB  [1024][1024]
  short* QK  = (short*)(ws + 16777216);          // 16 MB  [4096][2048]
  short* Vtg = (short*)(ws + 33554432);          //  8 MB  [32*64][2048]
  short* AO  = (short*)(ws + 41943040);          //  8 MB  [4096][1024]

  cvt_all<<<4096, 256, 0, stream>>>(x, w_qkv, w_proj, Xb, Wq, Wp);

  // qkv GEMM: 768 blocks, XCD owns 3 B-col panels (768KB L2-resident)
  gemm_db<0, 1, 3><<<dim3(768), 256, 0, stream>>>(Xb, Wq, QK, Vtg, nullptr,
                                                  1024, QSCALE, 4096, 3072, 1024);

  attn_fwd<<<dim3(512), 256, 0, stream>>>(QK, Vtg, AO);

  // proj GEMM: 256 blocks, XCD owns 1 B-col panel (256KB L2-resident)
  gemm_db<1, 0, 1><<<dim3(256), 256, 0, stream>>>(AO, Wp, out, nullptr, b_proj,
                                                  0, 1.0f, 4096, 1024, 1024);
}

// Round 16
// 102.937 us; speedup vs baseline: 1.0555x; 1.0051x over previous
//
#include <hip/hip_runtime.h>
#include <hip/hip_bf16.h>
#include <stdint.h>

typedef __attribute__((ext_vector_type(4))) float f32x4;
typedef __attribute__((ext_vector_type(16))) float f32x16;
typedef __attribute__((ext_vector_type(8))) short bf16x8;
typedef __attribute__((ext_vector_type(4))) short bf16x4;
typedef unsigned short ushort_t;

#define QSCALE 0.18033688f   // 0.125 * log2(e): softmax runs in exp2 domain

__device__ inline short f2bf(float f) {
  unsigned u = __builtin_bit_cast(unsigned, f);
  u += 0x7fffu + ((u >> 16) & 1u);   // RNE
  return (short)(u >> 16);
}

__device__ inline void gload_lds16(const void* g, void* l) {
  __builtin_amdgcn_global_load_lds(
      (const __attribute__((address_space(1))) void*)g,
      (__attribute__((address_space(3))) void*)l, 16, 0, 0);
}

__device__ inline unsigned cvtpk(float a, float b) {
  unsigned r;
  asm("v_cvt_pk_bf16_f32 %0, %1, %2" : "=v"(r) : "v"(a), "v"(b));
  return r;
}

__device__ inline void swap32u(unsigned& a, unsigned& b) {
  asm("v_permlane32_swap_b32 %0, %1" : "+v"(a), "+v"(b));
}

// ---------------- fused fp32 -> bf16 convert (x, w_qkv, w_proj), grid-stride ----------------
__global__ __launch_bounds__(256) void cvt_all(const float* __restrict__ x,
                                               const float* __restrict__ wq,
                                               const float* __restrict__ wp,
                                               short* __restrict__ Xb,
                                               short* __restrict__ Wq,
                                               short* __restrict__ Wp) {
  for (int i = blockIdx.x * 256 + threadIdx.x; i < 1048576; i += 2048 * 256) {
    const float* s;
    short* d;
    int off;
    if (i < 524288)       { s = x;  d = Xb; off = i; }
    else if (i < 917504)  { s = wq; d = Wq; off = i - 524288; }
    else                  { s = wp; d = Wp; off = i - 917504; }
    const float4* sv = (const float4*)s;
    float4 a = sv[2 * off], b = sv[2 * off + 1];
    bf16x8 o;
    o[0] = f2bf(a.x); o[1] = f2bf(a.y); o[2] = f2bf(a.z); o[3] = f2bf(a.w);
    o[4] = f2bf(b.x); o[5] = f2bf(b.y); o[6] = f2bf(b.z); o[7] = f2bf(b.w);
    ((bf16x8*)d)[off] = o;
  }
}

// ---------------- 128x128 BK=64 double-buffer counted-vmcnt GEMM: C = A * B^T ----------------
// T1 XCD swizzle: 1-D grid, xcd = id&7 owns BXPX consecutive B-column panels.
// SPLITV=1 (qkv): cols<2048 -> QK (q pre-scaled); cols>=2048 -> Vtg via LDS transpose.
template <int F32OUT, int SPLITV, int BXPX>
__global__ __launch_bounds__(256, 2) void gemm_db(const short* __restrict__ A,
                                                  const short* __restrict__ B,
                                                  void* __restrict__ Cv,
                                                  short* __restrict__ Vtg,
                                                  const float* __restrict__ bias,
                                                  int scale_cols, float scale_val,
                                                  int M, int N, int K) {
  __shared__ char smem[65536];
  short* Ab0 = (short*)smem;                 // [2][128*64]
  short* Bb0 = (short*)(smem + 32768);       // [2][128*64]
  const int tid = threadIdx.x, wv = tid >> 6, ln = tid & 63;
  const int wm = wv >> 1, wn = wv & 1;       // 2x2 waves, 64x64 each
  const int id = blockIdx.x;
  const int xcd = id & 7, local = id >> 3;
  const int bx = xcd * BXPX + local % BXPX;
  const int by = local / BXPX;
  const int bn0 = bx * 128, bm0 = by * 128;
  const int nt = K >> 6;                     // BK = 64

  const int srow = ln >> 3;
  const int scol = ((ln & 7) ^ (ln >> 3)) * 8;
  const int fln = ln & 15;
  const int fk = ln >> 4;

  f32x4 acc[4][4] = {};

  auto stage = [&](int t, int s) {
    const size_t k0 = (size_t)t << 6;
#pragma unroll
    for (int rd = 0; rd < 4; rd++) {
      const int ch = 4 * wv + rd;
      gload_lds16(A + (size_t)(bm0 + ch * 8 + srow) * K + k0 + scol,
                  (char*)(Ab0 + s * 8192) + ch * 1024);
      gload_lds16(B + (size_t)(bn0 + ch * 8 + srow) * K + k0 + scol,
                  (char*)(Bb0 + s * 8192) + ch * 1024);
    }
  };

  stage(0, 0);
  stage(1, 1);
  asm volatile("s_waitcnt vmcnt(8)" ::: "memory");
  __builtin_amdgcn_s_barrier();
  __builtin_amdgcn_sched_barrier(0);

  for (int t = 0; t < nt; t++) {
    const int s = t & 1;
    const char* Ap = (const char*)(Ab0 + s * 8192);
    const char* Bp = (const char*)(Bb0 + s * 8192);

    bf16x8 af[4][2], bf[4][2];
#pragma unroll
    for (int m = 0; m < 4; m++) {
      const int R = wm * 64 + m * 16 + fln;
#pragma unroll
      for (int kk = 0; kk < 2; kk++)
        af[m][kk] = *(const bf16x8*)(Ap + R * 128 + ((((kk << 2) | fk) ^ (R & 7)) << 4));
    }
#pragma unroll
    for (int n = 0; n < 4; n++) {
      const int R = wn * 64 + n * 16 + fln;
#pragma unroll
      for (int kk = 0; kk < 2; kk++)
        bf[n][kk] = *(const bf16x8*)(Bp + R * 128 + ((((kk << 2) | fk) ^ (R & 7)) << 4));
    }

    __builtin_amdgcn_s_setprio(1);
#pragma unroll
    for (int kk = 0; kk < 2; kk++)
#pragma unroll
      for (int m = 0; m < 4; m++)
#pragma unroll
        for (int n = 0; n < 4; n++)
          acc[m][n] = __builtin_amdgcn_mfma_f32_16x16x32_bf16(af[m][kk], bf[n][kk], acc[m][n], 0, 0, 0);
    __builtin_amdgcn_s_setprio(0);

    if (t + 1 < nt) {
      __builtin_amdgcn_s_barrier();
      if (t + 2 < nt) {
        stage(t + 2, s);
        asm volatile("s_waitcnt vmcnt(8)" ::: "memory");
      } else {
        asm volatile("s_waitcnt vmcnt(0)" ::: "memory");
      }
      __builtin_amdgcn_s_barrier();
      __builtin_amdgcn_sched_barrier(0);
    }
  }

  // ---------- epilogue ----------
  if constexpr (SPLITV) {
    if (bn0 >= 2048) {
      // V-block: coalesce the transpose through LDS (64KB free after K-loop)
      __syncthreads();
      short* Vl = (short*)smem;   // [128 f][136 tok] (pad 8 vs bank stride)
#pragma unroll
      for (int m = 0; m < 4; m++) {
        const int tok0 = wm * 64 + m * 16 + fk * 4;
#pragma unroll
        for (int n = 0; n < 4; n++) {
          const int f_loc = wn * 64 + n * 16 + fln;
          bf16x4 w;
#pragma unroll
          for (int j = 0; j < 4; j++) w[j] = f2bf(acc[m][n][j]);
          *(bf16x4*)(Vl + f_loc * 136 + tok0) = w;
        }
      }
      __syncthreads();
      const int fbase = bn0 - 2048, bb = bm0 >> 11, ntok0 = bm0 & 2047;
#pragma unroll
      for (int pass = 0; pass < 8; pass++) {
        const int f_loc = wv * 32 + pass * 4 + (ln >> 4);
        const int f = fbase + f_loc;
        const int g = (bb * 16 + (f >> 6)) * 64 + (f & 63);
        bf16x8 w = *(const bf16x8*)(Vl + f_loc * 136 + (ln & 15) * 8);
        *(bf16x8*)(Vtg + (size_t)g * 2048 + ntok0 + (ln & 15) * 8) = w;
      }
      return;
    }
  }

  const int r0 = bm0 + wm * 64, c0 = bn0 + wn * 64;
  const int fg4 = fk * 4;
#pragma unroll
  for (int m = 0; m < 4; m++) {
    const int row0 = r0 + m * 16 + fg4;
#pragma unroll
    for (int n = 0; n < 4; n++) {
      const int col = c0 + n * 16 + fln;
      if constexpr (SPLITV) {
        const float sc = (col < scale_cols) ? scale_val : 1.0f;
#pragma unroll
        for (int j = 0; j < 4; j++)
          ((short*)Cv)[(size_t)(row0 + j) * 2048 + col] = f2bf(acc[m][n][j] * sc);
      } else {
#pragma unroll
        for (int j = 0; j < 4; j++) {
          float v = acc[m][n][j];
          if (col < scale_cols) v *= scale_val;
          if (F32OUT) ((float*)Cv)[(size_t)(row0 + j) * N + col] = v + bias[col];
          else        ((short*)Cv)[(size_t)(row0 + j) * N + col] = f2bf(v);
        }
      }
    }
  }
}

// ---------------- flash attention: T3/T4 counted-vmcnt pipeline (R11-best) ----------------
__global__ __launch_bounds__(256, 2) void attn_fwd(const short* __restrict__ QK,
                                                   const short* __restrict__ Vtg,
                                                   short* __restrict__ AO) {
  __shared__ short Ks[3][64 * 64];
  __shared__ short Vt[3][64 * 64];
  const int tid = threadIdx.x, wv = tid >> 6, ln = tid & 63;
  const int lq = ln & 31, hi = ln >> 5;
  const int id = blockIdx.x;
  const int c = (id & 7) * 64 + (id >> 3);   // XCD swizzle: 4 heads per XCD
  const int qt = c & 15, bh = c >> 4;
  const int b = bh >> 4, h = bh & 15;
  const short* base = QK + (size_t)(b * 2048) * 2048 + h * 64;
  const short* Kg = base + 1024;
  const short* Vg = Vtg + (size_t)bh * 64 * 2048;
  const int qrow = qt * 128 + wv * 32 + lq;

  bf16x8 qf[4];
  {
    const short* Qrow = base + (size_t)qrow * 2048;
#pragma unroll
    for (int ds = 0; ds < 4; ds++)
      qf[ds] = *(const bf16x8*)(Qrow + ds * 16 + hi * 8);
  }

  const int krow = ln >> 3;
  const int kcol = ((ln & 7) ^ (ln >> 3)) * 8;

  float l_run = 0.f;
  f32x16 o0 = {}, o1 = {};

#define STAGE(t, s)                                                              \
  {                                                                              \
    _Pragma("unroll")                                                            \
    for (int rd = 0; rd < 2; rd++) {                                             \
      const int r8 = 16 * wv + 8 * rd + krow;                                    \
      gload_lds16(Kg + (size_t)((t) * 64 + r8) * 2048 + kcol,                    \
                  (char*)Ks[s] + (2 * wv + rd) * 1024);                          \
      gload_lds16(Vg + (size_t)r8 * 2048 + (t) * 64 + kcol,                      \
                  (char*)Vt[s] + (2 * wv + rd) * 1024);                          \
    }                                                                            \
  }

  STAGE(0, 0);
  STAGE(1, 1);

  for (int t = 0; t < 32; t++) {
    const int s = t % 3;
    if (t < 31) asm volatile("s_waitcnt vmcnt(4)" ::: "memory");
    else        asm volatile("s_waitcnt vmcnt(0)" ::: "memory");
    __builtin_amdgcn_s_barrier();
    __builtin_amdgcn_sched_barrier(0);
    if (t + 2 < 32) STAGE(t + 2, (t + 2) % 3);

    f32x16 c0 = {}, c1 = {};
    const char* Kb = (const char*)Ks[s];
    __builtin_amdgcn_s_setprio(1);
#pragma unroll
    for (int ds = 0; ds < 4; ds++) {
      const int cp = (ds * 2 + hi) ^ (lq & 7);
      bf16x8 ka0 = *(const bf16x8*)(Kb + lq * 128 + cp * 16);
      bf16x8 ka1 = *(const bf16x8*)(Kb + (32 + lq) * 128 + cp * 16);
      c0 = __builtin_amdgcn_mfma_f32_32x32x16_bf16(ka0, qf[ds], c0, 0, 0, 0);
      c1 = __builtin_amdgcn_mfma_f32_32x32x16_bf16(ka1, qf[ds], c1, 0, 0, 0);
    }
    __builtin_amdgcn_s_setprio(0);

#pragma unroll
    for (int r = 0; r < 16; r++) c0[r] = __builtin_amdgcn_exp2f(c0[r]);
#pragma unroll
    for (int r = 0; r < 16; r++) c1[r] = __builtin_amdgcn_exp2f(c1[r]);
    {
      float st[8];
#pragma unroll
      for (int r = 0; r < 8; r++)
        st[r] = (c0[2 * r] + c0[2 * r + 1]) + (c1[2 * r] + c1[2 * r + 1]);
#pragma unroll
      for (int r = 0; r < 4; r++) st[r] += st[r + 4];
      l_run += (st[0] + st[1]) + (st[2] + st[3]);
    }

    bf16x8 pa[4];
#pragma unroll
    for (int cs = 0; cs < 2; cs++) {
      const f32x16& p = cs ? c1 : c0;
#pragma unroll
      for (int ksl = 0; ksl < 2; ksl++) {
        unsigned A0 = cvtpk(p[8 * ksl + 0], p[8 * ksl + 1]);
        unsigned A1 = cvtpk(p[8 * ksl + 2], p[8 * ksl + 3]);
        unsigned B0 = cvtpk(p[8 * ksl + 4], p[8 * ksl + 5]);
        unsigned B1 = cvtpk(p[8 * ksl + 6], p[8 * ksl + 7]);
        swap32u(A0, B0);
        swap32u(A1, B1);
        union { unsigned u[4]; bf16x8 v; } tmp;
        tmp.u[0] = A0; tmp.u[1] = A1; tmp.u[2] = B0; tmp.u[3] = B1;
        pa[cs * 2 + ksl] = tmp.v;
      }
    }

    const char* Vb = (const char*)Vt[s];
    __builtin_amdgcn_s_setprio(1);
#pragma unroll
    for (int ks = 0; ks < 4; ks++) {
      const int cp = (ks * 2 + hi) ^ (lq & 7);
      bf16x8 va0 = *(const bf16x8*)(Vb + lq * 128 + cp * 16);
      bf16x8 va1 = *(const bf16x8*)(Vb + (32 + lq) * 128 + cp * 16);
      o0 = __builtin_amdgcn_mfma_f32_32x32x16_bf16(va0, pa[ks], o0, 0, 0, 0);
      o1 = __builtin_amdgcn_mfma_f32_32x32x16_bf16(va1, pa[ks], o1, 0, 0, 0);
    }
    __builtin_amdgcn_s_setprio(0);
  }
#undef STAGE

  l_run += __shfl_xor(l_run, 32);
  const float inv = __builtin_amdgcn_rcpf(l_run);
  short* Arow = AO + ((size_t)(b * 2048) + qrow) * 1024 + h * 64;
#pragma unroll
  for (int dt = 0; dt < 2; dt++) {
    const f32x16& o = dt ? o1 : o0;
#pragma unroll
    for (int g = 0; g < 4; g++) {
      bf16x4 w;
#pragma unroll
      for (int i = 0; i < 4; i++) w[i] = f2bf(o[4 * g + i] * inv);
      *(bf16x4*)(Arow + dt * 32 + 8 * g + 4 * hi) = w;
    }
  }
}

// ---------------- launch ----------------
extern "C" void kernel_launch(void* const* d_in, const int* in_sizes, int n_in,
                              void* d_out, int out_size, void* d_ws, size_t ws_size,
                              hipStream_t stream) {
  const float* x = (const float*)d_in[0];       // [2,2048,1024]
  const float* w_qkv = (const float*)d_in[1];   // [3072,1024]
  const float* w_proj = (const float*)d_in[2];  // [1024,1024]
  const float* b_proj = (const float*)d_in[3];  // [1024]
  float* out = (float*)d_out;                   // [2,2048,1024] fp32

  char* ws = (char*)d_ws;
  short* Xb  = (short*)(ws + 0);                 //  8 MB  [4096][1024]
  short* Wq  = (short*)(ws + 8388608);           //  6 MB  [3072][1024]
  short* Wp  = (short*)(ws + 14680064);          //  2 MB  [1024][1024]
  short* QK  = (short*)(ws + 16777216);          // 16 MB  [4096][2048]
  short* Vtg = (short*)(ws + 33554432);          //  8 MB  [32*64][2048]
  short* AO  = (short*)(ws + 41943040);          //  8 MB  [4096][1024]

  cvt_all<<<2048, 256, 0, stream>>>(x, w_qkv, w_proj, Xb, Wq, Wp);

  // qkv GEMM: 768 blocks, XCD owns 3 B-col panels (768KB L2-resident)
  gemm_db<0, 1, 3><<<dim3(768), 256, 0, stream>>>(Xb, Wq, QK, Vtg, nullptr,
                                                  1024, QSCALE, 4096, 3072, 1024);

  attn_fwd<<<dim3(512), 256, 0, stream>>>(QK, Vtg, AO);

  // proj GEMM: 256 blocks, XCD owns 1 B-col panel (256KB L2-resident)
  gemm_db<1, 0, 1><<<dim3(256), 256, 0, stream>>>(AO, Wp, out, nullptr, b_proj,
                                                  0, 1.0f, 4096, 1024, 1024);
}